// Round 12
// baseline (230.068 us; speedup 1.0000x reference)
//
#include <hip/hip_runtime.h>
#include <hip/hip_bf16.h>

// ---- problem constants ----
#define Bb    2
#define Cc    128
#define HWp   16384    // 128*128 (one channel plane)
#define NBLK  64
#define BNOD  16
#define NPix  256
#define Nn    1024

// ---- ws layout (float element offsets) ----
#define OQ    0u        // Q      [B][NBLK][BNOD][NP]   524288
#define OF    524288u   // feats RAW v [B][N][C]        262144  (consumers apply invn)
#define ONSQ  2883584u  // nsq    [B][N]                  2048  (direct store now)
#define OFN   3670016u  // FnT    bf16 [S*B][C][N]
#define OGI   4456448u  // gi     [S][B][N]
#define OGJ   4462592u  // gj     [S][B][N]
#define OOUT  4468736u  // Fr-init / final out [S][B][N][C]
#define OBNS  5255168u  // bn sum [S][C]
#define OBNQ  5255552u  // bn sq  [S][C]
#define OPOOL 5255936u  // pool   [S][B][C]
#define OYS   5258240u  // ys     [S][B][N][C]
#define OAW   6306816u  // masked-gated W bf16 [6][1024][1024]
// OFT (featsT RAW f32 [B][C][N]) overlays OYS: live only proj->fm_adj.
#define OFT   OYS

typedef short s8v  __attribute__((ext_vector_type(8)));
typedef float f4v  __attribute__((ext_vector_type(4)));

__device__ __forceinline__ short f2bf(float f) {
    __hip_bfloat16 h = __float2bfloat16(f);
    return *reinterpret_cast<short*>(&h);
}

__device__ __forceinline__ float nrm_inv(float nsq) {
    return 1.0f / fmaxf(sqrtf(nsq), 1e-12f);
}

// ---------------- fused proj: x staged ONCE in LDS (128 KB tile) ----------------
// grid (64 blk, 2 b) x 256 threads, ~158 KB LDS, 1 block/CU.
// Phase A: thread = pixel -> distances + per-thread softmax (no cross-lane reduce).
// Phase B: thread = (channel, node-octet) -> s1, raw v, nsq (direct store).
__global__ __launch_bounds__(256, 1) void k_proj(const float* __restrict__ x,
                                                 const float* __restrict__ anchor,
                                                 const float* __restrict__ sigma_raw,
                                                 float* __restrict__ ws) {
    const int blk = blockIdx.x, b = blockIdx.y;
    const int t = threadIdx.x;
    __shared__ __align__(16) float pixl[128][260];  // 133.1 KB: x-tile [c][p] (+pad)
    __shared__ __align__(16) float smB[4096];       // 16 KB: pairs[128][16]f2 | Qs[16][256]
    __shared__ float vbuf[16][132];                 // 8.4 KB
    __shared__ float S0s[16];
    float2 (*pairs)[16] = (float2(*)[16])smB;
    float (*Qs)[256] = (float(*)[256])smB;

    if (blk == 0 && b == 0) {
        for (int i = t; i < 1536; i += 256) ws[OBNS + i] = 0.0f;   // BNS+BNQ+POOL
    }
    // node params -> LDS
    for (int e = t; e < 2048; e += 256) {
        int k = e >> 7, c = e & 127;
        int n = blk * 16 + k;
        float a    = anchor[n * 128 + c];
        float sr   = sigma_raw[n * 128 + c];
        float isig = 1.0f + __expf(-sr);       // 1/sigmoid(sr)
        pairs[c][k] = make_float2(isig, a * isig);
    }
    // burst-stage the whole x tile: 128 c x 256 pixels (8192 float4 loads)
    const int h0 = (blk >> 3) * 16, w0 = (blk & 7) * 16;
    for (int e = t; e < 8192; e += 256) {
        int cc = e >> 6, f4 = e & 63;
        int pr = f4 >> 2, wq = (f4 & 3) * 4;
        *(float4*)&pixl[cc][f4 * 4] =
            *(const float4*)(x + ((size_t)b * Cc + cc) * HWp
                             + (size_t)(h0 + pr) * 128 + w0 + wq);
    }
    __syncthreads();
    // ---- phase A: per-pixel distances over all 128 channels ----
    const int p = t;                            // 256 threads = 256 pixels
    float acc[16];
#pragma unroll
    for (int k = 0; k < 16; k++) acc[k] = 0.0f;
    for (int c = 0; c < 128; c++) {
        float pv = pixl[c][p];
#pragma unroll
        for (int k = 0; k < 16; k += 2) {
            float4 pr = *(const float4*)&pairs[c][k];
            float d0 = fmaf(pv, pr.x, -pr.y);
            float d1 = fmaf(pv, pr.z, -pr.w);
            acc[k]     = fmaf(d0, d0, acc[k]);
            acc[k + 1] = fmaf(d1, d1, acc[k + 1]);
        }
    }
    __syncthreads();   // pairs dead -> smB becomes Qs
    {
        float m = acc[0];
#pragma unroll
        for (int k = 1; k < 16; k++) m = fminf(m, acc[k]);
        float ssum = 0.0f, ev[16];
#pragma unroll
        for (int k = 0; k < 16; k++) { ev[k] = __expf(0.5f * (m - acc[k])); ssum += ev[k]; }
        float inv = 1.0f / ssum;
        float* Qp = ws + OQ + ((size_t)(b * 64 + blk) * 16) * 256 + p;
#pragma unroll
        for (int k = 0; k < 16; k++) {
            float q = ev[k] * inv;
            Qs[k][p] = q;
            Qp[k * 256] = q;
        }
    }
    __syncthreads();
    if (t < 16) {
        float s0 = 0.0f;
        for (int pc = 0; pc < 64; pc++) {
            float4 q = *(const float4*)&Qs[t][pc * 4];
            s0 += (q.x + q.y) + (q.z + q.w);
        }
        S0s[t] = s0;
    }
    __syncthreads();
    // ---- phase B: s1[k][c] = sum_p Q[k][p] * x[c][p]; raw v ----
    {
        const int c = t & 127, hf = t >> 7;     // channel, node-octet half
        const int k0 = hf * 8;
        float s1[8];
#pragma unroll
        for (int j = 0; j < 8; j++) s1[j] = 0.0f;
        for (int pc = 0; pc < 64; pc++) {
            float4 pv = *(const float4*)&pixl[c][pc * 4];
#pragma unroll
            for (int j = 0; j < 8; j++) {
                float4 qv = *(const float4*)&Qs[k0 + j][pc * 4];
                s1[j] = fmaf(pv.x, qv.x, fmaf(pv.y, qv.y, fmaf(pv.z, qv.z, fmaf(pv.w, qv.w, s1[j]))));
            }
        }
#pragma unroll
        for (int j = 0; j < 8; j++) {
            const int k = k0 + j;
            const int n = blk * 16 + k;
            float S0 = S0s[k];
            float i0 = 1.0f / (S0 + 1e-9f);
            float isig = 1.0f + __expf(-sigma_raw[n * 128 + c]);
            float aa   = anchor[n * 128 + c];
            float v = isig * (s1[j] - aa * S0) * i0;
            vbuf[k][c] = v;
        }
    }
    __syncthreads();
    if (t < 16) {
        float nsq = 0.0f;
        for (int c = 0; c < 128; c++) {
            float v = vbuf[t][c];
            nsq = fmaf(v, v, nsq);
        }
        ws[ONSQ + (size_t)b * Nn + blk * 16 + t] = nsq;   // direct store, no atomic
    }
    // raw v out (coalesced)
    for (int e = t; e < 2048; e += 256) {
        int k = e >> 7, c = e & 127;
        ws[OF + ((size_t)b * Nn + blk * 16 + k) * 128 + c] = vbuf[k][c];
    }
    for (int e = t; e < 2048; e += 256) {
        int c = e >> 4, k = e & 15;
        ws[OFT + ((size_t)b * 128 + c) * 1024 + blk * 16 + k] = vbuf[k][c];
    }
}

// ---------------- merged: feats@W (Fr -> OOUT init) || adj GEMM + mask/gate -> bf16 W ----------------
__global__ __launch_bounds__(256) void k_fm_adj(const float* __restrict__ W_root,
                                                const float* __restrict__ W_nbr,
                                                const float* __restrict__ wgs,
                                                const float* __restrict__ wgd,
                                                const float* __restrict__ b_gate,
                                                float* __restrict__ ws) {
    __shared__ __align__(16) float sm[8704];   // 34.8 KB shared by both branches
    const int bid = blockIdx.x;
    const int t = threadIdx.x;
    if (bid < 384) {
        const int tile = bid & 63, b = (bid >> 6) & 1, s = bid >> 7;
        __shared__ float innl[16];
        float (*fl)[132] = (float(*)[132])sm;
        const float* F = ws + OF + ((size_t)b * Nn + tile * 16) * 128;
        for (int e = t; e < 16 * 128; e += 256) fl[e >> 7][e & 127] = F[e];
        if (t < 16) innl[t] = nrm_inv(ws[ONSQ + (size_t)b * Nn + tile * 16 + t]);
        __syncthreads();
        const int cout = t & 127, ih = t >> 7;
        float ar[8], an[8];
#pragma unroll
        for (int q = 0; q < 8; q++) { ar[q] = 0.0f; an[q] = 0.0f; }
        const float* Wr = W_root + s * 16384;
        const float* Wn = W_nbr + s * 16384;
        for (int cin = 0; cin < 128; cin++) {
            float wr = Wr[cin * 128 + cout];
            float wn = Wn[cin * 128 + cout];
#pragma unroll
            for (int q = 0; q < 8; q++) {
                float f = fl[ih * 8 + q][cin];
                ar[q] = fmaf(f, wr, ar[q]);
                an[q] = fmaf(f, wn, an[q]);
            }
        }
        const int sb = s * 2 + b;
#pragma unroll
        for (int q = 0; q < 8; q++) {
            int row = tile * 16 + ih * 8 + q;
            ws[OOUT + ((size_t)sb * Nn + row) * 128 + cout] = ar[q] * innl[ih * 8 + q];
        }
        {
            short hb[8];
#pragma unroll
            for (int q = 0; q < 8; q++) hb[q] = f2bf(an[q] * innl[ih * 8 + q]);
            short* fnb = (short*)(ws + OFN);
            *(int4*)(fnb + (((size_t)sb * 128 + cout) << 10) + tile * 16 + ih * 8) = *(int4*)hb;
        }
        if (t < 16) {
            int row = tile * 16 + t;
            float g1 = 0.0f, g2 = 0.0f;
            for (int c = 0; c < 128; c++) {
                float f = fl[t][c];
                g1 = fmaf(f, wgs[s * 128 + c], g1);
                g2 = fmaf(f, wgd[s * 128 + c], g2);
            }
            ws[OGI + (size_t)sb * Nn + row] = g1 * innl[t];
            ws[OGJ + (size_t)sb * Nn + row] = g2 * innl[t];
        }
    } else {
        const int e = bid - 384;
        const int jt = e & 15, it = (e >> 4) & 15, b = e >> 8;
        __shared__ float gis[3][64], gjs[3][64], bgs[3];
        __shared__ float iinv[64], jinv[64];
        if (t < 192) {
            int s = t >> 6, ii = t & 63;
            gis[s][ii] = ws[OGI + (size_t)(s * 2 + b) * Nn + it * 64 + ii];
            gjs[s][ii] = ws[OGJ + (size_t)(s * 2 + b) * Nn + jt * 64 + ii];
        }
        if (t < 3) bgs[t] = b_gate[t];
        if (t >= 192 && t < 256) {
            int ii = t - 192;
            iinv[ii] = nrm_inv(ws[ONSQ + (size_t)b * Nn + it * 64 + ii]);
            jinv[ii] = nrm_inv(ws[ONSQ + (size_t)b * Nn + jt * 64 + ii]);
        }
        float (*FiT)[68] = (float(*)[68])sm;
        float (*FjT)[68] = (float(*)[68])(sm + 4352);
        const float* FT = ws + OFT + (size_t)b * 128 * 1024;
        const int tx = t & 15, ty = t >> 4;
        float acc[4][4];
#pragma unroll
        for (int r = 0; r < 4; r++)
#pragma unroll
            for (int ee = 0; ee < 4; ee++) acc[r][ee] = 0.0f;
        for (int ch = 0; ch < 2; ch++) {
            __syncthreads();
#pragma unroll
            for (int k = 0; k < 4; k++) {
                int idx = k * 256 + t;
                int cc = idx >> 4, n4 = (idx & 15) * 4;
                *(float4*)&FiT[cc][n4] =
                    *(const float4*)(FT + (size_t)(ch * 64 + cc) * 1024 + it * 64 + n4);
                *(float4*)&FjT[cc][n4] =
                    *(const float4*)(FT + (size_t)(ch * 64 + cc) * 1024 + jt * 64 + n4);
            }
            __syncthreads();
            for (int c = 0; c < 64; c++) {
                float4 fi = *(const float4*)&FiT[c][ty * 4];
                float4 fj = *(const float4*)&FjT[c][tx * 4];
                const float fiv[4] = {fi.x, fi.y, fi.z, fi.w};
                const float fjv[4] = {fj.x, fj.y, fj.z, fj.w};
#pragma unroll
                for (int r = 0; r < 4; r++)
#pragma unroll
                    for (int ee = 0; ee < 4; ee++)
                        acc[r][ee] = fmaf(fiv[r], fjv[ee], acc[r][ee]);
            }
        }
        short* AW = (short*)(ws + OAW);
#pragma unroll
        for (int s = 0; s < 3; s++) {
            const int sb = s * 2 + b;
#pragma unroll
            for (int r = 0; r < 4; r++) {
                const int i = it * 64 + ty * 4 + r;
                const int iblk = i >> 4;
                const float giv = gis[s][ty * 4 + r];
                const float ivr = iinv[ty * 4 + r];
                short o[4];
#pragma unroll
                for (int ee = 0; ee < 4; ee++) {
                    const int j = jt * 64 + tx * 4 + ee;
                    float a = acc[r][ee] * ivr * jinv[tx * 4 + ee];
                    bool same = iblk == (j >> 4);
                    bool pass;
                    if (s == 0)      pass = (a > 0.7f) && same;
                    else if (s == 1) pass = (a > 0.5f) && !same;
                    else             pass = (a > 0.3f);
                    float g = 1.0f / (1.0f + __expf(-(giv + gjs[s][tx * 4 + ee] + bgs[s])));
                    o[ee] = f2bf(pass ? a * g : 0.0f);
                }
                *(int2*)(AW + (((size_t)sb << 20) + ((size_t)i << 10) + jt * 64 + tx * 4)) = *(int2*)o;
            }
        }
    }
}

// ---------------- merged MFMA aggregation + Fr fold + BN stats (R8-verified) ----------------
// grid (32 mt, 6 sb) = 192 blocks; 256 threads; full K=1024 per block.
__global__ __launch_bounds__(256) void k_aggbn(float* __restrict__ ws) {
    const int mt = blockIdx.x, sb = blockIdx.y;
    const int s = sb >> 1;
    const int t = threadIdx.x;
    const int i0 = mt * 32;
    __shared__ short A_s[32][136];   // 8.7 KB
    __shared__ short B_s[128][136];  // 34.8 KB
    __shared__ float bnS[128], bnQ[128];
    const short* AWp = (const short*)(ws + OAW) + ((size_t)sb << 20);
    const short* fnb = (const short*)(ws + OFN) + ((size_t)sb * 128 << 10);
    const int wid = t >> 6, lane = t & 63, quad = lane >> 4, l15 = lane & 15;
    f4v acc00 = {0,0,0,0}, acc01 = {0,0,0,0}, acc10 = {0,0,0,0}, acc11 = {0,0,0,0};
    if (t < 128) { bnS[t] = 0.0f; bnQ[t] = 0.0f; }

    for (int chunk = 0; chunk < 8; chunk++) {
        const int j0 = chunk * 128;
        __syncthreads();
        {
            const int i = t >> 3, kk = (t & 7) << 4;
            const short* src = AWp + ((size_t)(i0 + i) << 10) + j0 + kk;
            *(int4*)&A_s[i][kk]     = *(const int4*)(src);
            *(int4*)&A_s[i][kk + 8] = *(const int4*)(src + 8);
        }
        {
            const int c = t >> 1, k0l = (t & 1) << 6;
            const short* src = fnb + ((size_t)c << 10) + j0 + k0l;
#pragma unroll
            for (int e = 0; e < 8; e++)
                *(int4*)&B_s[c][k0l + e * 8] = *(const int4*)(src + e * 8);
        }
        __syncthreads();
#pragma unroll
        for (int ks = 0; ks < 4; ks++) {
            const int ko = ks * 32 + quad * 8;
            s8v a0 = *(const s8v*)&A_s[l15][ko];
            s8v a1 = *(const s8v*)&A_s[16 + l15][ko];
            s8v b0 = *(const s8v*)&B_s[wid * 32 + l15][ko];
            s8v b1 = *(const s8v*)&B_s[wid * 32 + 16 + l15][ko];
            acc00 = __builtin_amdgcn_mfma_f32_16x16x32_bf16(a0, b0, acc00, 0, 0, 0);
            acc01 = __builtin_amdgcn_mfma_f32_16x16x32_bf16(a0, b1, acc01, 0, 0, 0);
            acc10 = __builtin_amdgcn_mfma_f32_16x16x32_bf16(a1, b0, acc10, 0, 0, 0);
            acc11 = __builtin_amdgcn_mfma_f32_16x16x32_bf16(a1, b1, acc11, 0, 0, 0);
        }
    }
    {
        float* outp = ws + OOUT + ((size_t)sb * Nn) * 128;
        const int c0 = wid * 32 + l15;
        const int n0 = i0 + quad * 4;
        float s1a = 0.0f, s2a = 0.0f, s1b = 0.0f, s2b = 0.0f;
#pragma unroll
        for (int r = 0; r < 4; r++) {
            size_t ia = (size_t)(n0 + r) * 128 + c0;
            size_t ib = (size_t)(n0 + r) * 128 + c0 + 16;
            size_t ic = (size_t)(n0 + 16 + r) * 128 + c0;
            size_t id = (size_t)(n0 + 16 + r) * 128 + c0 + 16;
            float va = outp[ia] + acc00[r];
            float vb = outp[ib] + acc01[r];
            float vc = outp[ic] + acc10[r];
            float vd = outp[id] + acc11[r];
            outp[ia] = va; outp[ib] = vb; outp[ic] = vc; outp[id] = vd;
            s1a += va + vc; s2a = fmaf(va, va, fmaf(vc, vc, s2a));
            s1b += vb + vd; s2b = fmaf(vb, vb, fmaf(vd, vd, s2b));
        }
        atomicAdd(&bnS[c0], s1a);      atomicAdd(&bnQ[c0], s2a);
        atomicAdd(&bnS[c0 + 16], s1b); atomicAdd(&bnQ[c0 + 16], s2b);
    }
    __syncthreads();
    if (t < 128) {
        atomicAdd(&ws[OBNS + s * 128 + t], bnS[t]);
        atomicAdd(&ws[OBNQ + s * 128 + t], bnQ[t]);
    }
}

// ---------------- BN + residual + NodeAtt + relu + max-pool (R8-verified) ----------------
__global__ __launch_bounds__(256) void k_bn_att(const float* __restrict__ bn_gamma,
                                                const float* __restrict__ bn_beta,
                                                const float* __restrict__ att_W,
                                                const float* __restrict__ att_b,
                                                float* __restrict__ ws) {
    const int tile8 = blockIdx.x, b = blockIdx.y, s = blockIdx.z;
    const int t = threadIdx.x;
    __shared__ float hl[8][132];
    __shared__ float innl[8];
    const int sb = s * 2 + b;
    const int cthr = t & 127, ih = t >> 7;
    if (t < 8) innl[t] = nrm_inv(ws[ONSQ + (size_t)b * Nn + tile8 * 8 + t]);
    float mu = ws[OBNS + s * 128 + cthr] * (1.0f / 2048.0f);
    float ms = ws[OBNQ + s * 128 + cthr] * (1.0f / 2048.0f);
    float var = ms - mu * mu;
    float gam = bn_gamma[s * 128 + cthr];
    float bet = bn_beta[s * 128 + cthr];
    float scal = gam * rsqrtf(var + 1e-5f);
    const float* outp = ws + OOUT + ((size_t)sb * Nn + tile8 * 8) * 128;
    const float* F = ws + OF + ((size_t)b * Nn + tile8 * 8) * 128;
    __syncthreads();
#pragma unroll
    for (int q = 0; q < 4; q++) {
        int il = ih * 4 + q;
        float v = outp[(size_t)il * 128 + cthr];
        hl[il][cthr] = scal * (v - mu) + bet + F[(size_t)il * 128 + cthr] * innl[il];
    }
    __syncthreads();
    float acc[4] = {0, 0, 0, 0};
    const float* AW = att_W + s * 16384;
    for (int cin = 0; cin < 128; cin++) {
        float w = AW[cin * 128 + cthr];
#pragma unroll
        for (int q = 0; q < 4; q++) acc[q] = fmaf(hl[ih * 4 + q][cin], w, acc[q]);
    }
    float ab = att_b[s * 128 + cthr];
    float* ys = ws + OYS + ((size_t)sb * Nn + tile8 * 8) * 128;
    float mx = 0.0f;
#pragma unroll
    for (int q = 0; q < 4; q++) {
        int il = ih * 4 + q;
        float h = hl[il][cthr];
        float sg = 1.0f / (1.0f + __expf(-(acc[q] + ab)));
        float y = fmaxf(sg * h, 0.0f);
        ys[(size_t)il * 128 + cthr] = y;
        mx = fmaxf(mx, y);
    }
    atomicMax((unsigned int*)(ws + OPOOL + sb * 128 + cthr), __float_as_uint(mx));
}

// ---------------- fused: MLP(pool) + coef + combination + lineFu + reprojection + residual (R8-verified) ----------------
__global__ __launch_bounds__(256) void k_fuse_reproj(const float* __restrict__ mlp_W1,
                                                     const float* __restrict__ mlp_b1,
                                                     const float* __restrict__ mlp_W2,
                                                     const float* __restrict__ mlp_b2,
                                                     const float* __restrict__ lineA_w,
                                                     const float* __restrict__ lineA_b,
                                                     const float* __restrict__ lineFu_W,
                                                     const float* __restrict__ lineFu_b,
                                                     const float* __restrict__ x,
                                                     float* __restrict__ ws,
                                                     float* __restrict__ out) {
    const int tile = blockIdx.x, b = blockIdx.y, chh = blockIdx.z;
    const int t = threadIdx.x;
    __shared__ float fl[16][132];
    __shared__ __align__(16) float ylT[64][20];
    __shared__ float av[3];
    __shared__ float p2l[3][128];
    __shared__ float poolz[128], z1l[128], zz[2][128];
    const int co = t & 127, hf = t >> 7;
    for (int s = 0; s < 3; s++) {
        if (t < 128) poolz[t] = ws[OPOOL + (s * 2 + b) * 128 + t];
        __syncthreads();
        {
            float a = 0.0f;
            const float* W1p = mlp_W1 + s * 16384 + co;
            for (int cin = hf * 64; cin < hf * 64 + 64; cin++)
                a = fmaf(poolz[cin], W1p[cin * 128], a);
            zz[hf][co] = a;
        }
        __syncthreads();
        if (t < 128) z1l[t] = fmaxf(zz[0][t] + zz[1][t] + mlp_b1[s * 128 + t], 0.0f);
        __syncthreads();
        {
            float a = 0.0f;
            const float* W2p = mlp_W2 + s * 16384 + co;
            for (int cin = hf * 64; cin < hf * 64 + 64; cin++)
                a = fmaf(z1l[cin], W2p[cin * 128], a);
            zz[hf][co] = a;
        }
        __syncthreads();
        if (t < 128)
            p2l[s][t] = 1.0f / (1.0f + __expf(-(zz[0][t] + zz[1][t] + mlp_b2[s * 128 + t])));
        __syncthreads();
    }
    if (t < 3) {
        float acc = lineA_b[t];
        for (int c = 0; c < 128; c++)
            acc = fmaf(p2l[t][c], lineA_w[t * 128 + c], acc);
        av[t] = acc;
    }
    __syncthreads();
    const float m = fmaxf(av[0], fmaxf(av[1], av[2]));
    const float e0 = __expf(av[0] - m), e1 = __expf(av[1] - m), e2 = __expf(av[2] - m);
    const float sinv = 1.0f / (e0 + e1 + e2);
    const int cthr = t & 127, ih = t >> 7;
    const float c0 = e0 * sinv * p2l[0][cthr];
    const float c1 = e1 * sinv * p2l[1][cthr];
    const float c2 = e2 * sinv * p2l[2][cthr];
#pragma unroll
    for (int q = 0; q < 8; q++) {
        int il = ih * 8 + q;
        size_t row = (size_t)(tile * 16 + il) * 128 + cthr;
        float v = c0 * ws[OYS + (size_t)(0 * 2 + b) * Nn * 128 + row]
                + c1 * ws[OYS + (size_t)(1 * 2 + b) * Nn * 128 + row]
                + c2 * ws[OYS + (size_t)(2 * 2 + b) * Nn * 128 + row];
        fl[il][cthr] = v;
    }
    __syncthreads();
    {
        const int coo = chh * 64 + (t & 63), rg = t >> 6;
        float acc[4] = {0, 0, 0, 0};
        for (int cin = 0; cin < 128; cin++) {
            float w = lineFu_W[cin * 128 + coo];
#pragma unroll
            for (int q = 0; q < 4; q++) acc[q] = fmaf(fl[rg * 4 + q][cin], w, acc[q]);
        }
        const float bb = lineFu_b[coo];
#pragma unroll
        for (int q = 0; q < 4; q++) ylT[t & 63][rg * 4 + q] = acc[q] + bb;
    }
    float qv[16];
    const float* Qg = ws + OQ + (size_t)(b * 64 + tile) * 16 * 256;
#pragma unroll
    for (int k = 0; k < 16; k++) qv[k] = Qg[k * 256 + t];
    __syncthreads();
    const int h = (tile >> 3) * 16 + (t >> 4);
    const int w = (tile & 7) * 16 + (t & 15);
    const float* xp = x + (size_t)b * Cc * HWp + (size_t)h * 128 + w;
    float* op = out + (size_t)b * Cc * HWp + (size_t)h * 128 + w;
    for (int c = 0; c < 64; c++) {
        float4 y0 = *(const float4*)&ylT[c][0];
        float4 y1 = *(const float4*)&ylT[c][4];
        float4 y2 = *(const float4*)&ylT[c][8];
        float4 y3 = *(const float4*)&ylT[c][12];
        float r = 0.0f;
        r = fmaf(qv[0],  y0.x, r); r = fmaf(qv[1],  y0.y, r);
        r = fmaf(qv[2],  y0.z, r); r = fmaf(qv[3],  y0.w, r);
        r = fmaf(qv[4],  y1.x, r); r = fmaf(qv[5],  y1.y, r);
        r = fmaf(qv[6],  y1.z, r); r = fmaf(qv[7],  y1.w, r);
        r = fmaf(qv[8],  y2.x, r); r = fmaf(qv[9],  y2.y, r);
        r = fmaf(qv[10], y2.z, r); r = fmaf(qv[11], y2.w, r);
        r = fmaf(qv[12], y3.x, r); r = fmaf(qv[13], y3.y, r);
        r = fmaf(qv[14], y3.z, r); r = fmaf(qv[15], y3.w, r);
        const size_t off = (size_t)(chh * 64 + c) * HWp;
        op[off] = r + xp[off];
    }
}

extern "C" void kernel_launch(void* const* d_in, const int* in_sizes, int n_in,
                              void* d_out, int out_size, void* d_ws, size_t ws_size,
                              hipStream_t stream) {
    const float* x         = (const float*)d_in[0];
    const float* anchor    = (const float*)d_in[1];
    const float* sigma_raw = (const float*)d_in[2];
    const float* W_root    = (const float*)d_in[3];
    const float* W_nbr     = (const float*)d_in[4];
    const float* wgs       = (const float*)d_in[5];
    const float* wgd       = (const float*)d_in[6];
    const float* b_gate    = (const float*)d_in[7];
    const float* bn_gamma  = (const float*)d_in[8];
    const float* bn_beta   = (const float*)d_in[9];
    const float* att_W     = (const float*)d_in[10];
    const float* att_b     = (const float*)d_in[11];
    const float* mlp_W1    = (const float*)d_in[12];
    const float* mlp_b1    = (const float*)d_in[13];
    const float* mlp_W2    = (const float*)d_in[14];
    const float* mlp_b2    = (const float*)d_in[15];
    const float* lineA_w   = (const float*)d_in[16];
    const float* lineA_b   = (const float*)d_in[17];
    const float* lineFu_W  = (const float*)d_in[18];
    const float* lineFu_b  = (const float*)d_in[19];
    float* out = (float*)d_out;
    float* ws = (float*)d_ws;

    k_proj       <<<dim3(64, 2),     dim3(256), 0, stream>>>(x, anchor, sigma_raw, ws);
    k_fm_adj     <<<dim3(896),       dim3(256), 0, stream>>>(W_root, W_nbr, wgs, wgd, b_gate, ws);
    k_aggbn      <<<dim3(32, 6),     dim3(256), 0, stream>>>(ws);
    k_bn_att     <<<dim3(128, 2, 3), dim3(256), 0, stream>>>(bn_gamma, bn_beta, att_W, att_b, ws);
    k_fuse_reproj<<<dim3(64, 2, 2),  dim3(256), 0, stream>>>(mlp_W1, mlp_b1, mlp_W2, mlp_b2,
                                                             lineA_w, lineA_b, lineFu_W, lineFu_b,
                                                             x, ws, out);
}

// Round 13
// 216.478 us; speedup vs baseline: 1.0628x; 1.0628x over previous
//
#include <hip/hip_runtime.h>
#include <hip/hip_bf16.h>

// ---- problem constants ----
#define Bb    2
#define Cc    128
#define HWp   16384    // 128*128 (one channel plane)
#define NBLK  64
#define BNOD  16
#define NPix  256
#define Nn    1024

// ---- ws layout (float element offsets) ----
#define OQ    0u        // Q      [B][NBLK][BNOD][NP]   524288
#define OF    524288u   // feats RAW v [B][N][C]        262144  (consumers apply invn)
#define ONSQ  2883584u  // nsq    [B][N]                  2048
#define OFN   3670016u  // FnT    bf16 [S*B][C][N]
#define OGI   4456448u  // gi     [S][B][N]
#define OGJ   4462592u  // gj     [S][B][N]
#define OOUT  4468736u  // Fr-init / final out [S][B][N][C]
#define OBNS  5255168u  // bn sum [S][C]
#define OBNQ  5255552u  // bn sq  [S][C]
#define OPOOL 5255936u  // pool   [S][B][C]
#define OYS   5258240u  // ys     [S][B][N][C]
#define OAW   6306816u  // masked-gated W bf16 [6][1024][1024]
// OFT (featsT RAW f32 [B][C][N]) overlays OYS: live only proj2->fm_adj.
#define OFT   OYS

typedef short s8v  __attribute__((ext_vector_type(8)));
typedef float f4v  __attribute__((ext_vector_type(4)));

__device__ __forceinline__ short f2bf(float f) {
    __hip_bfloat16 h = __float2bfloat16(f);
    return *reinterpret_cast<short*>(&h);
}

__device__ __forceinline__ float nrm_inv(float nsq) {
    return 1.0f / fmaxf(sqrtf(nsq), 1e-12f);
}

// ---------------- P1: logits + softmax over 16 nodes -> Q ----------------
// 1024 blocks x 128 threads (32 pixels/block).
__global__ __launch_bounds__(128) void k_proj1(const float* __restrict__ x,
                                               const float* __restrict__ anchor,
                                               const float* __restrict__ sigma_raw,
                                               float* __restrict__ ws) {
    const int blk = blockIdx.x, b = blockIdx.y, pg = blockIdx.z;   // pg in 0..7
    const int t = threadIdx.x;
    if (blk == 0 && b == 0 && pg == 0) {
        for (int i = t; i < 1536; i += 128) ws[OBNS + i] = 0.0f;   // BNS+BNQ+POOL
    }
    if (blk == 1 && b == 0 && pg == 0) {
        for (int i = t; i < 2048; i += 128) ws[ONSQ + i] = 0.0f;   // nsq[B][N]
    }
    __shared__ __align__(16) float2 pairs[128][16];   // 16 KB
    __shared__ float accp[4][32][17];                 // 8.7 KB
    for (int e = t; e < 2048; e += 128) {
        int k = e >> 7, c = e & 127;
        int n = blk * 16 + k;
        float a    = anchor[n * 128 + c];
        float sr   = sigma_raw[n * 128 + c];
        float isig = 1.0f + __expf(-sr);       // 1/sigmoid(sr)
        pairs[c][k] = make_float2(isig, a * isig);
    }
    __syncthreads();
    const int pl = t & 31, cq = t >> 5;
    const int p = pg * 32 + pl;
    const int h = (blk >> 3) * 16 + (p >> 4);
    const int w = (blk & 7) * 16 + (p & 15);
    const float* xp = x + (size_t)b * Cc * HWp + (size_t)h * 128 + w;
    float acc[16];
#pragma unroll
    for (int k = 0; k < 16; k++) acc[k] = 0.0f;
    for (int c = cq * 32; c < cq * 32 + 32; c++) {
        float pv = xp[(size_t)c * HWp];
#pragma unroll
        for (int k = 0; k < 16; k += 2) {
            float4 pr = *(const float4*)&pairs[c][k];
            float d0 = fmaf(pv, pr.x, -pr.y);
            float d1 = fmaf(pv, pr.z, -pr.w);
            acc[k]     = fmaf(d0, d0, acc[k]);
            acc[k + 1] = fmaf(d1, d1, acc[k + 1]);
        }
    }
#pragma unroll
    for (int k = 0; k < 16; k++) accp[cq][pl][k] = acc[k];
    __syncthreads();
    if (t < 32) {
        float a2[16];
#pragma unroll
        for (int k = 0; k < 16; k++)
            a2[k] = (accp[0][t][k] + accp[1][t][k]) + (accp[2][t][k] + accp[3][t][k]);
        float m = a2[0];
#pragma unroll
        for (int k = 1; k < 16; k++) m = fminf(m, a2[k]);
        float ssum = 0.0f, ev[16];
#pragma unroll
        for (int k = 0; k < 16; k++) { ev[k] = __expf(0.5f * (m - a2[k])); ssum += ev[k]; }
        float inv = 1.0f / ssum;
        float* Qp = ws + OQ + ((size_t)(b * 64 + blk) * 16) * 256 + (pg * 32 + t);
#pragma unroll
        for (int k = 0; k < 16; k++) Qp[k * 256] = ev[k] * inv;
    }
}

// ---------------- P2: weighted node residuals, RAW v + nsq partials ----------------
__global__ __launch_bounds__(256) void k_proj2(const float* __restrict__ x,
                                               const float* __restrict__ anchor,
                                               const float* __restrict__ sigma_raw,
                                               float* __restrict__ ws) {
    const int blk = blockIdx.x, b = blockIdx.y, cg2 = blockIdx.z;   // cg2 in 0..3
    const int t = threadIdx.x;
    __shared__ __align__(16) float Ql[16][256];    // 16 KB
    __shared__ __align__(16) float pixl[32][260];  // 33.3 KB
    __shared__ float vbuf[16][36];                 // 2.3 KB
    __shared__ float S0s[16];
    const float* Qg = ws + OQ + (size_t)(b * 64 + blk) * 16 * 256;
    for (int e = t; e < 1024; e += 256)
        *(float4*)&Ql[e >> 6][(e & 63) * 4] = *(const float4*)(Qg + (size_t)e * 4);
    __syncthreads();
    if (t < 16) {
        float s0 = 0.0f;
        for (int pc = 0; pc < 64; pc++) {
            float4 q = *(const float4*)&Ql[t][pc * 4];
            s0 += (q.x + q.y) + (q.z + q.w);
        }
        S0s[t] = s0;
    }
    const int h0 = (blk >> 3) * 16, w0 = (blk & 7) * 16;
    for (int e = t; e < 2048; e += 256) {
        int cc = e >> 6, f4 = e & 63;
        int pr = f4 >> 2, wq = (f4 & 3) * 4;
        *(float4*)&pixl[cc][f4 * 4] =
            *(const float4*)(x + ((size_t)b * Cc + cg2 * 32 + cc) * HWp
                             + (size_t)(h0 + pr) * 128 + w0 + wq);
    }
    __syncthreads();
    const int cq = t & 31;
    const int k0 = (t >> 5) * 2;
    const int n0 = blk * 16 + k0;
    const int c = cg2 * 32 + cq;
    const float S0a = S0s[k0], S0b = S0s[k0 + 1];
    const float i0a = 1.0f / (S0a + 1e-9f);
    const float i0b = 1.0f / (S0b + 1e-9f);
    float s1a = 0.0f, s1b = 0.0f;
    for (int pc = 0; pc < 64; pc++) {
        float4 pv = *(const float4*)&pixl[cq][pc * 4];
        float4 qa = *(const float4*)&Ql[k0][pc * 4];
        float4 qb = *(const float4*)&Ql[k0 + 1][pc * 4];
        s1a = fmaf(pv.x, qa.x, fmaf(pv.y, qa.y, fmaf(pv.z, qa.z, fmaf(pv.w, qa.w, s1a))));
        s1b = fmaf(pv.x, qb.x, fmaf(pv.y, qb.y, fmaf(pv.z, qb.z, fmaf(pv.w, qb.w, s1b))));
    }
    float isa = 1.0f + __expf(-sigma_raw[(n0)     * 128 + c]);
    float isb = 1.0f + __expf(-sigma_raw[(n0 + 1) * 128 + c]);
    float aa  = anchor[(n0)     * 128 + c];
    float ab  = anchor[(n0 + 1) * 128 + c];
    float va = isa * (s1a - aa * S0a) * i0a;
    float vb = isb * (s1b - ab * S0b) * i0b;
    ws[OF + ((size_t)b * Nn + n0)     * 128 + c] = va;
    ws[OF + ((size_t)b * Nn + n0 + 1) * 128 + c] = vb;
    vbuf[k0][cq]     = va;
    vbuf[k0 + 1][cq] = vb;
    float nsqa = va * va, nsqb = vb * vb;
#pragma unroll
    for (int off = 16; off >= 1; off >>= 1) {
        nsqa += __shfl_xor(nsqa, off, 64);
        nsqb += __shfl_xor(nsqb, off, 64);
    }
    if (cq == 0) {
        atomicAdd(&ws[ONSQ + (size_t)b * Nn + n0],     nsqa);
        atomicAdd(&ws[ONSQ + (size_t)b * Nn + n0 + 1], nsqb);
    }
    __syncthreads();
    for (int e = t; e < 512; e += 256) {
        int k = e & 15, cl = e >> 4;
        ws[OFT + ((size_t)b * 128 + cg2 * 32 + cl) * 1024 + blk * 16 + k] = vbuf[k][cl];
    }
}

// ---------------- merged: feats@W (Fr -> OOUT init) || adj GEMM + mask/gate -> bf16 W ----------------
__global__ __launch_bounds__(256) void k_fm_adj(const float* __restrict__ W_root,
                                                const float* __restrict__ W_nbr,
                                                const float* __restrict__ wgs,
                                                const float* __restrict__ wgd,
                                                const float* __restrict__ b_gate,
                                                float* __restrict__ ws) {
    __shared__ __align__(16) float sm[8704];   // 34.8 KB shared by both branches
    const int bid = blockIdx.x;
    const int t = threadIdx.x;
    if (bid < 384) {
        const int tile = bid & 63, b = (bid >> 6) & 1, s = bid >> 7;
        __shared__ float innl[16];
        float (*fl)[132] = (float(*)[132])sm;
        const float* F = ws + OF + ((size_t)b * Nn + tile * 16) * 128;
        for (int e = t; e < 16 * 128; e += 256) fl[e >> 7][e & 127] = F[e];
        if (t < 16) innl[t] = nrm_inv(ws[ONSQ + (size_t)b * Nn + tile * 16 + t]);
        __syncthreads();
        const int cout = t & 127, ih = t >> 7;
        float ar[8], an[8];
#pragma unroll
        for (int q = 0; q < 8; q++) { ar[q] = 0.0f; an[q] = 0.0f; }
        const float* Wr = W_root + s * 16384;
        const float* Wn = W_nbr + s * 16384;
        for (int cin = 0; cin < 128; cin++) {
            float wr = Wr[cin * 128 + cout];
            float wn = Wn[cin * 128 + cout];
#pragma unroll
            for (int q = 0; q < 8; q++) {
                float f = fl[ih * 8 + q][cin];
                ar[q] = fmaf(f, wr, ar[q]);
                an[q] = fmaf(f, wn, an[q]);
            }
        }
        const int sb = s * 2 + b;
#pragma unroll
        for (int q = 0; q < 8; q++) {
            int row = tile * 16 + ih * 8 + q;
            ws[OOUT + ((size_t)sb * Nn + row) * 128 + cout] = ar[q] * innl[ih * 8 + q];
        }
        {
            short hb[8];
#pragma unroll
            for (int q = 0; q < 8; q++) hb[q] = f2bf(an[q] * innl[ih * 8 + q]);
            short* fnb = (short*)(ws + OFN);
            *(int4*)(fnb + (((size_t)sb * 128 + cout) << 10) + tile * 16 + ih * 8) = *(int4*)hb;
        }
        if (t < 16) {
            int row = tile * 16 + t;
            float g1 = 0.0f, g2 = 0.0f;
            for (int c = 0; c < 128; c++) {
                float f = fl[t][c];
                g1 = fmaf(f, wgs[s * 128 + c], g1);
                g2 = fmaf(f, wgd[s * 128 + c], g2);
            }
            ws[OGI + (size_t)sb * Nn + row] = g1 * innl[t];
            ws[OGJ + (size_t)sb * Nn + row] = g2 * innl[t];
        }
    } else {
        const int e = bid - 384;
        const int jt = e & 15, it = (e >> 4) & 15, b = e >> 8;
        __shared__ float gis[3][64], gjs[3][64], bgs[3];
        __shared__ float iinv[64], jinv[64];
        if (t < 192) {
            int s = t >> 6, ii = t & 63;
            gis[s][ii] = ws[OGI + (size_t)(s * 2 + b) * Nn + it * 64 + ii];
            gjs[s][ii] = ws[OGJ + (size_t)(s * 2 + b) * Nn + jt * 64 + ii];
        }
        if (t < 3) bgs[t] = b_gate[t];
        if (t >= 192 && t < 256) {
            int ii = t - 192;
            iinv[ii] = nrm_inv(ws[ONSQ + (size_t)b * Nn + it * 64 + ii]);
            jinv[ii] = nrm_inv(ws[ONSQ + (size_t)b * Nn + jt * 64 + ii]);
        }
        float (*FiT)[68] = (float(*)[68])sm;
        float (*FjT)[68] = (float(*)[68])(sm + 4352);
        const float* FT = ws + OFT + (size_t)b * 128 * 1024;
        const int tx = t & 15, ty = t >> 4;
        float acc[4][4];
#pragma unroll
        for (int r = 0; r < 4; r++)
#pragma unroll
            for (int ee = 0; ee < 4; ee++) acc[r][ee] = 0.0f;
        for (int ch = 0; ch < 2; ch++) {
            __syncthreads();
#pragma unroll
            for (int k = 0; k < 4; k++) {
                int idx = k * 256 + t;
                int cc = idx >> 4, n4 = (idx & 15) * 4;
                *(float4*)&FiT[cc][n4] =
                    *(const float4*)(FT + (size_t)(ch * 64 + cc) * 1024 + it * 64 + n4);
                *(float4*)&FjT[cc][n4] =
                    *(const float4*)(FT + (size_t)(ch * 64 + cc) * 1024 + jt * 64 + n4);
            }
            __syncthreads();
            for (int c = 0; c < 64; c++) {
                float4 fi = *(const float4*)&FiT[c][ty * 4];
                float4 fj = *(const float4*)&FjT[c][tx * 4];
                const float fiv[4] = {fi.x, fi.y, fi.z, fi.w};
                const float fjv[4] = {fj.x, fj.y, fj.z, fj.w};
#pragma unroll
                for (int r = 0; r < 4; r++)
#pragma unroll
                    for (int ee = 0; ee < 4; ee++)
                        acc[r][ee] = fmaf(fiv[r], fjv[ee], acc[r][ee]);
            }
        }
        short* AW = (short*)(ws + OAW);
#pragma unroll
        for (int s = 0; s < 3; s++) {
            const int sb = s * 2 + b;
#pragma unroll
            for (int r = 0; r < 4; r++) {
                const int i = it * 64 + ty * 4 + r;
                const int iblk = i >> 4;
                const float giv = gis[s][ty * 4 + r];
                const float ivr = iinv[ty * 4 + r];
                short o[4];
#pragma unroll
                for (int ee = 0; ee < 4; ee++) {
                    const int j = jt * 64 + tx * 4 + ee;
                    float a = acc[r][ee] * ivr * jinv[tx * 4 + ee];
                    bool same = iblk == (j >> 4);
                    bool pass;
                    if (s == 0)      pass = (a > 0.7f) && same;
                    else if (s == 1) pass = (a > 0.5f) && !same;
                    else             pass = (a > 0.3f);
                    float g = 1.0f / (1.0f + __expf(-(giv + gjs[s][tx * 4 + ee] + bgs[s])));
                    o[ee] = f2bf(pass ? a * g : 0.0f);
                }
                *(int2*)(AW + (((size_t)sb << 20) + ((size_t)i << 10) + jt * 64 + tx * 4)) = *(int2*)o;
            }
        }
    }
}

// ---------------- merged MFMA aggregation + Fr fold + BN stats ----------------
// grid (32 mt, 6 sb) = 192 blocks; 256 threads; full K=1024 per block.
__global__ __launch_bounds__(256) void k_aggbn(float* __restrict__ ws) {
    const int mt = blockIdx.x, sb = blockIdx.y;
    const int s = sb >> 1;
    const int t = threadIdx.x;
    const int i0 = mt * 32;
    __shared__ short A_s[32][136];   // 8.7 KB
    __shared__ short B_s[128][136];  // 34.8 KB
    __shared__ float bnS[128], bnQ[128];
    const short* AWp = (const short*)(ws + OAW) + ((size_t)sb << 20);
    const short* fnb = (const short*)(ws + OFN) + ((size_t)sb * 128 << 10);
    const int wid = t >> 6, lane = t & 63, quad = lane >> 4, l15 = lane & 15;
    f4v acc00 = {0,0,0,0}, acc01 = {0,0,0,0}, acc10 = {0,0,0,0}, acc11 = {0,0,0,0};
    if (t < 128) { bnS[t] = 0.0f; bnQ[t] = 0.0f; }

    for (int chunk = 0; chunk < 8; chunk++) {
        const int j0 = chunk * 128;
        __syncthreads();
        {
            const int i = t >> 3, kk = (t & 7) << 4;
            const short* src = AWp + ((size_t)(i0 + i) << 10) + j0 + kk;
            *(int4*)&A_s[i][kk]     = *(const int4*)(src);
            *(int4*)&A_s[i][kk + 8] = *(const int4*)(src + 8);
        }
        {
            const int c = t >> 1, k0l = (t & 1) << 6;
            const short* src = fnb + ((size_t)c << 10) + j0 + k0l;
#pragma unroll
            for (int e = 0; e < 8; e++)
                *(int4*)&B_s[c][k0l + e * 8] = *(const int4*)(src + e * 8);
        }
        __syncthreads();
#pragma unroll
        for (int ks = 0; ks < 4; ks++) {
            const int ko = ks * 32 + quad * 8;
            s8v a0 = *(const s8v*)&A_s[l15][ko];
            s8v a1 = *(const s8v*)&A_s[16 + l15][ko];
            s8v b0 = *(const s8v*)&B_s[wid * 32 + l15][ko];
            s8v b1 = *(const s8v*)&B_s[wid * 32 + 16 + l15][ko];
            acc00 = __builtin_amdgcn_mfma_f32_16x16x32_bf16(a0, b0, acc00, 0, 0, 0);
            acc01 = __builtin_amdgcn_mfma_f32_16x16x32_bf16(a0, b1, acc01, 0, 0, 0);
            acc10 = __builtin_amdgcn_mfma_f32_16x16x32_bf16(a1, b0, acc10, 0, 0, 0);
            acc11 = __builtin_amdgcn_mfma_f32_16x16x32_bf16(a1, b1, acc11, 0, 0, 0);
        }
    }
    {
        float* outp = ws + OOUT + ((size_t)sb * Nn) * 128;
        const int c0 = wid * 32 + l15;
        const int n0 = i0 + quad * 4;
        float s1a = 0.0f, s2a = 0.0f, s1b = 0.0f, s2b = 0.0f;
#pragma unroll
        for (int r = 0; r < 4; r++) {
            size_t ia = (size_t)(n0 + r) * 128 + c0;
            size_t ib = (size_t)(n0 + r) * 128 + c0 + 16;
            size_t ic = (size_t)(n0 + 16 + r) * 128 + c0;
            size_t id = (size_t)(n0 + 16 + r) * 128 + c0 + 16;
            float va = outp[ia] + acc00[r];
            float vb = outp[ib] + acc01[r];
            float vc = outp[ic] + acc10[r];
            float vd = outp[id] + acc11[r];
            outp[ia] = va; outp[ib] = vb; outp[ic] = vc; outp[id] = vd;
            s1a += va + vc; s2a = fmaf(va, va, fmaf(vc, vc, s2a));
            s1b += vb + vd; s2b = fmaf(vb, vb, fmaf(vd, vd, s2b));
        }
        atomicAdd(&bnS[c0], s1a);      atomicAdd(&bnQ[c0], s2a);
        atomicAdd(&bnS[c0 + 16], s1b); atomicAdd(&bnQ[c0 + 16], s2b);
    }
    __syncthreads();
    if (t < 128) {
        atomicAdd(&ws[OBNS + s * 128 + t], bnS[t]);
        atomicAdd(&ws[OBNQ + s * 128 + t], bnQ[t]);
    }
}

// ---------------- BN + residual + NodeAtt + relu + max-pool ----------------
__global__ __launch_bounds__(256) void k_bn_att(const float* __restrict__ bn_gamma,
                                                const float* __restrict__ bn_beta,
                                                const float* __restrict__ att_W,
                                                const float* __restrict__ att_b,
                                                float* __restrict__ ws) {
    const int tile8 = blockIdx.x, b = blockIdx.y, s = blockIdx.z;
    const int t = threadIdx.x;
    __shared__ float hl[8][132];
    __shared__ float innl[8];
    const int sb = s * 2 + b;
    const int cthr = t & 127, ih = t >> 7;
    if (t < 8) innl[t] = nrm_inv(ws[ONSQ + (size_t)b * Nn + tile8 * 8 + t]);
    float mu = ws[OBNS + s * 128 + cthr] * (1.0f / 2048.0f);
    float ms = ws[OBNQ + s * 128 + cthr] * (1.0f / 2048.0f);
    float var = ms - mu * mu;
    float gam = bn_gamma[s * 128 + cthr];
    float bet = bn_beta[s * 128 + cthr];
    float scal = gam * rsqrtf(var + 1e-5f);
    const float* outp = ws + OOUT + ((size_t)sb * Nn + tile8 * 8) * 128;
    const float* F = ws + OF + ((size_t)b * Nn + tile8 * 8) * 128;
    __syncthreads();
#pragma unroll
    for (int q = 0; q < 4; q++) {
        int il = ih * 4 + q;
        float v = outp[(size_t)il * 128 + cthr];
        hl[il][cthr] = scal * (v - mu) + bet + F[(size_t)il * 128 + cthr] * innl[il];
    }
    __syncthreads();
    float acc[4] = {0, 0, 0, 0};
    const float* AW = att_W + s * 16384;
    for (int cin = 0; cin < 128; cin++) {
        float w = AW[cin * 128 + cthr];
#pragma unroll
        for (int q = 0; q < 4; q++) acc[q] = fmaf(hl[ih * 4 + q][cin], w, acc[q]);
    }
    float ab = att_b[s * 128 + cthr];
    float* ys = ws + OYS + ((size_t)sb * Nn + tile8 * 8) * 128;
    float mx = 0.0f;
#pragma unroll
    for (int q = 0; q < 4; q++) {
        int il = ih * 4 + q;
        float h = hl[il][cthr];
        float sg = 1.0f / (1.0f + __expf(-(acc[q] + ab)));
        float y = fmaxf(sg * h, 0.0f);
        ys[(size_t)il * 128 + cthr] = y;
        mx = fmaxf(mx, y);
    }
    atomicMax((unsigned int*)(ws + OPOOL + sb * 128 + cthr), __float_as_uint(mx));
}

// ---------------- fused: MLP(pool) + coef + combination + lineFu + reprojection + residual ----------------
// 2-way cout split (chh in {0,1}): grid (64,2,2) = 256 blocks.
__global__ __launch_bounds__(256) void k_fuse_reproj(const float* __restrict__ mlp_W1,
                                                     const float* __restrict__ mlp_b1,
                                                     const float* __restrict__ mlp_W2,
                                                     const float* __restrict__ mlp_b2,
                                                     const float* __restrict__ lineA_w,
                                                     const float* __restrict__ lineA_b,
                                                     const float* __restrict__ lineFu_W,
                                                     const float* __restrict__ lineFu_b,
                                                     const float* __restrict__ x,
                                                     float* __restrict__ ws,
                                                     float* __restrict__ out) {
    const int tile = blockIdx.x, b = blockIdx.y, chh = blockIdx.z;
    const int t = threadIdx.x;
    __shared__ float fl[16][132];
    __shared__ __align__(16) float ylT[64][20];
    __shared__ float av[3];
    __shared__ float p2l[3][128];
    __shared__ float poolz[128], z1l[128], zz[2][128];
    const int co = t & 127, hf = t >> 7;
    for (int s = 0; s < 3; s++) {
        if (t < 128) poolz[t] = ws[OPOOL + (s * 2 + b) * 128 + t];
        __syncthreads();
        {
            float a = 0.0f;
            const float* W1p = mlp_W1 + s * 16384 + co;
            for (int cin = hf * 64; cin < hf * 64 + 64; cin++)
                a = fmaf(poolz[cin], W1p[cin * 128], a);
            zz[hf][co] = a;
        }
        __syncthreads();
        if (t < 128) z1l[t] = fmaxf(zz[0][t] + zz[1][t] + mlp_b1[s * 128 + t], 0.0f);
        __syncthreads();
        {
            float a = 0.0f;
            const float* W2p = mlp_W2 + s * 16384 + co;
            for (int cin = hf * 64; cin < hf * 64 + 64; cin++)
                a = fmaf(z1l[cin], W2p[cin * 128], a);
            zz[hf][co] = a;
        }
        __syncthreads();
        if (t < 128)
            p2l[s][t] = 1.0f / (1.0f + __expf(-(zz[0][t] + zz[1][t] + mlp_b2[s * 128 + t])));
        __syncthreads();
    }
    if (t < 3) {
        float acc = lineA_b[t];
        for (int c = 0; c < 128; c++)
            acc = fmaf(p2l[t][c], lineA_w[t * 128 + c], acc);
        av[t] = acc;
    }
    __syncthreads();
    const float m = fmaxf(av[0], fmaxf(av[1], av[2]));
    const float e0 = __expf(av[0] - m), e1 = __expf(av[1] - m), e2 = __expf(av[2] - m);
    const float sinv = 1.0f / (e0 + e1 + e2);
    const int cthr = t & 127, ih = t >> 7;
    const float c0 = e0 * sinv * p2l[0][cthr];
    const float c1 = e1 * sinv * p2l[1][cthr];
    const float c2 = e2 * sinv * p2l[2][cthr];
#pragma unroll
    for (int q = 0; q < 8; q++) {
        int il = ih * 8 + q;
        size_t row = (size_t)(tile * 16 + il) * 128 + cthr;
        float v = c0 * ws[OYS + (size_t)(0 * 2 + b) * Nn * 128 + row]
                + c1 * ws[OYS + (size_t)(1 * 2 + b) * Nn * 128 + row]
                + c2 * ws[OYS + (size_t)(2 * 2 + b) * Nn * 128 + row];
        fl[il][cthr] = v;
    }
    __syncthreads();
    {
        const int coo = chh * 64 + (t & 63), rg = t >> 6;
        float acc[4] = {0, 0, 0, 0};
        for (int cin = 0; cin < 128; cin++) {
            float w = lineFu_W[cin * 128 + coo];
#pragma unroll
            for (int q = 0; q < 4; q++) acc[q] = fmaf(fl[rg * 4 + q][cin], w, acc[q]);
        }
        const float bb = lineFu_b[coo];
#pragma unroll
        for (int q = 0; q < 4; q++) ylT[t & 63][rg * 4 + q] = acc[q] + bb;
    }
    float qv[16];
    const float* Qg = ws + OQ + (size_t)(b * 64 + tile) * 16 * 256;
#pragma unroll
    for (int k = 0; k < 16; k++) qv[k] = Qg[k * 256 + t];
    __syncthreads();
    const int h = (tile >> 3) * 16 + (t >> 4);
    const int w = (tile & 7) * 16 + (t & 15);
    const float* xp = x + (size_t)b * Cc * HWp + (size_t)h * 128 + w;
    float* op = out + (size_t)b * Cc * HWp + (size_t)h * 128 + w;
    for (int c = 0; c < 64; c++) {
        float4 y0 = *(const float4*)&ylT[c][0];
        float4 y1 = *(const float4*)&ylT[c][4];
        float4 y2 = *(const float4*)&ylT[c][8];
        float4 y3 = *(const float4*)&ylT[c][12];
        float r = 0.0f;
        r = fmaf(qv[0],  y0.x, r); r = fmaf(qv[1],  y0.y, r);
        r = fmaf(qv[2],  y0.z, r); r = fmaf(qv[3],  y0.w, r);
        r = fmaf(qv[4],  y1.x, r); r = fmaf(qv[5],  y1.y, r);
        r = fmaf(qv[6],  y1.z, r); r = fmaf(qv[7],  y1.w, r);
        r = fmaf(qv[8],  y2.x, r); r = fmaf(qv[9],  y2.y, r);
        r = fmaf(qv[10], y2.z, r); r = fmaf(qv[11], y2.w, r);
        r = fmaf(qv[12], y3.x, r); r = fmaf(qv[13], y3.y, r);
        r = fmaf(qv[14], y3.z, r); r = fmaf(qv[15], y3.w, r);
        const size_t off = (size_t)(chh * 64 + c) * HWp;
        op[off] = r + xp[off];
    }
}

extern "C" void kernel_launch(void* const* d_in, const int* in_sizes, int n_in,
                              void* d_out, int out_size, void* d_ws, size_t ws_size,
                              hipStream_t stream) {
    const float* x         = (const float*)d_in[0];
    const float* anchor    = (const float*)d_in[1];
    const float* sigma_raw = (const float*)d_in[2];
    const float* W_root    = (const float*)d_in[3];
    const float* W_nbr     = (const float*)d_in[4];
    const float* wgs       = (const float*)d_in[5];
    const float* wgd       = (const float*)d_in[6];
    const float* b_gate    = (const float*)d_in[7];
    const float* bn_gamma  = (const float*)d_in[8];
    const float* bn_beta   = (const float*)d_in[9];
    const float* att_W     = (const float*)d_in[10];
    const float* att_b     = (const float*)d_in[11];
    const float* mlp_W1    = (const float*)d_in[12];
    const float* mlp_b1    = (const float*)d_in[13];
    const float* mlp_W2    = (const float*)d_in[14];
    const float* mlp_b2    = (const float*)d_in[15];
    const float* lineA_w   = (const float*)d_in[16];
    const float* lineA_b   = (const float*)d_in[17];
    const float* lineFu_W  = (const float*)d_in[18];
    const float* lineFu_b  = (const float*)d_in[19];
    float* out = (float*)d_out;
    float* ws = (float*)d_ws;

    k_proj1      <<<dim3(64, 2, 8),  dim3(128), 0, stream>>>(x, anchor, sigma_raw, ws);
    k_proj2      <<<dim3(64, 2, 4),  dim3(256), 0, stream>>>(x, anchor, sigma_raw, ws);
    k_fm_adj     <<<dim3(896),       dim3(256), 0, stream>>>(W_root, W_nbr, wgs, wgd, b_gate, ws);
    k_aggbn      <<<dim3(32, 6),     dim3(256), 0, stream>>>(ws);
    k_bn_att     <<<dim3(128, 2, 3), dim3(256), 0, stream>>>(bn_gamma, bn_beta, att_W, att_b, ws);
    k_fuse_reproj<<<dim3(64, 2, 2),  dim3(256), 0, stream>>>(mlp_W1, mlp_b1, mlp_W2, mlp_b2,
                                                             lineA_w, lineA_b, lineFu_W, lineFu_b,
                                                             x, ws, out);
}